// Round 8
// baseline (203.396 us; speedup 1.0000x reference)
//
#include <hip/hip_runtime.h>

// Native clang vector type — required by __builtin_nontemporal_{load,store}
// (HIP_vector_type float4 is rejected). Supports elementwise +=.
typedef float f32x4 __attribute__((ext_vector_type(4)));

// Problem constants (from reference):
constexpr int kB  = 256;    // batch
constexpr int kN  = 1000;   // classes
constexpr int kA  = 32;     // attention parts
constexpr int kC  = 512;    // channels
constexpr int kAC = kA * kC;            // 16384 floats per (class or sample)
constexpr int kFeat  = kB * kAC;        // 4,194,304
constexpr int kCache = kN * kAC;        // 16,384,000
constexpr int kRows  = kB * kA;         // 8192 (b,a) rows of 512 floats

constexpr int kCacheSplit = 4;                  // blocks per class row
constexpr int kCacheBlks  = kN * kCacheSplit;   // 4000
constexpr int kF4PerClass = kAC / 4;            // 4096 float4
constexpr int kF4PerChunk = kF4PerClass / kCacheSplit;  // 1024
constexpr int kAccN       = kF4PerChunk / 256;  // 4 float4 per thread

constexpr int kExRowsPerBlk = 8;                // rows per exchange block
constexpr int kExBlks = kRows / kExRowsPerBlk;  // 1024
constexpr int kExIters = kExRowsPerBlk * 128 / 256;  // 4 float4 per thread

// ---------------------------------------------------------------------------
// Kernel 1: per-sample wave: cls[b] = argmax_n labels[b,n] (first-max), then
// lanes 0..31 compute the per-(b,a)-row source descriptor:
//   srcrow[row] = (rand_u[row] > 0.5) ? 0x80000000 | (cls*32 + a) : row
// ---------------------------------------------------------------------------
__global__ __launch_bounds__(256) void k_prep(
    const float* __restrict__ labels,
    const float* __restrict__ rand_u,
    int* __restrict__ cls,
    int* __restrict__ srcrow)
{
    const int wave = threadIdx.x >> 6;
    const int lane = threadIdx.x & 63;
    const int b = blockIdx.x * 4 + wave;
    const float* row = labels + (size_t)b * kN;
    float best = -3.4e38f;
    int   bidx = kN;
    for (int n = lane; n < kN; n += 64) {
        float v = row[n];                      // coalesced across lanes
        if (v > best) { best = v; bidx = n; }  // ascending n => first max kept
    }
    #pragma unroll
    for (int off = 32; off >= 1; off >>= 1) {  // butterfly: all lanes converge
        float ov = __shfl_xor(best, off, 64);
        int   oi = __shfl_xor(bidx, off, 64);
        if (ov > best || (ov == best && oi < bidx)) { best = ov; bidx = oi; }
    }
    if (lane == 0) cls[b] = bidx;
    if (lane < kA) {
        const int r = b * kA + lane;
        const float ru = rand_u[r];
        srcrow[r] = (ru > 0.5f) ? (int)(0x80000000u | (unsigned)(bidx * kA + lane))
                                : r;
    }
}

// ---------------------------------------------------------------------------
// Kernel 2: new_cache + new_count. One block per 16KB class-row quarter
// (4000 blocks). Explicit 4-deep load batch -> 4 stores keeps >=4 wave-loads
// in flight (bytes-in-flight is the BW limiter, see round-7 analysis).
// ---------------------------------------------------------------------------
__global__ __launch_bounds__(256) void k_cache(
    const float* __restrict__ features,
    const float* __restrict__ cache,
    const float* __restrict__ count,
    const int*   __restrict__ cls,
    float* __restrict__ out_cache,
    float* __restrict__ out_count)
{
    const int blk = blockIdx.x;
    const int t = threadIdx.x;
    const int n = blk >> 2;
    const int q = blk & 3;

    __shared__ unsigned long long masks[4];
    const int myc = cls[t];                          // coalesced 1KB read
    unsigned long long mb = __ballot(myc == n);
    if ((t & 63) == 0) masks[t >> 6] = mb;
    __syncthreads();                                 // drains only cls load

    unsigned long long m[4];
    int mtot = 0;
    #pragma unroll
    for (int w = 0; w < 4; ++w) { m[w] = masks[w]; mtot += __popcll(m[w]); }

    const size_t base = (size_t)n * kF4PerClass + (size_t)q * kF4PerChunk;
    const f32x4* src = (const f32x4*)cache + base;
    f32x4*       dst = (f32x4*)out_cache + base;

    // explicit 4-deep register batch: 4 loads in flight, then 4 stores
    f32x4 v0 = src[t];
    f32x4 v1 = src[t + 256];
    f32x4 v2 = src[t + 512];
    f32x4 v3 = src[t + 768];

    #pragma unroll
    for (int w = 0; w < 4; ++w) {
        unsigned long long mm = m[w];
        while (mm) {                                 // usually 0 iterations
            const int bit = __ffsll((long long)mm) - 1;
            mm &= mm - 1;
            const int b = w * 64 + bit;              // ascending b order
            const f32x4* f = (const f32x4*)features
                            + (size_t)b * kF4PerClass + (size_t)q * kF4PerChunk;
            f32x4 f0 = f[t];
            f32x4 f1 = f[t + 256];
            f32x4 f2 = f[t + 512];
            f32x4 f3 = f[t + 768];
            v0 += f0; v1 += f1; v2 += f2; v3 += f3;
        }
    }

    __builtin_nontemporal_store(v0, &dst[t]);
    __builtin_nontemporal_store(v1, &dst[t + 256]);
    __builtin_nontemporal_store(v2, &dst[t + 512]);
    __builtin_nontemporal_store(v3, &dst[t + 768]);

    if (t == 0 && q == 0) out_count[n] = count[n] + (float)mtot;
}

// ---------------------------------------------------------------------------
// Kernel 3: exch_features — 8 rows/block, 3-stage batched copy (4 srcrow
// loads in flight, then 4 vector loads in flight, then 4 stores).
// ---------------------------------------------------------------------------
__global__ __launch_bounds__(256) void k_exch(
    const float* __restrict__ features,
    const float* __restrict__ anchor,
    const int*   __restrict__ srcrow,
    float* __restrict__ out_feat)
{
    const int t  = threadIdx.x;
    const int j0 = blockIdx.x * (kExRowsPerBlk * 128);   // base float4 index
    const f32x4* features4 = (const f32x4*)features;
    const f32x4* anchor4   = (const f32x4*)anchor;
    f32x4*       out4      = (f32x4*)out_feat;

    int s[kExIters];
    #pragma unroll
    for (int k = 0; k < kExIters; ++k)               // 4 srcrow loads in flight
        s[k] = srcrow[(j0 + k * 256 + t) >> 7];

    f32x4 v[kExIters];
    #pragma unroll
    for (int k = 0; k < kExIters; ++k) {             // 4 vec loads in flight
        const int c4 = (j0 + k * 256 + t) & 127;
        const f32x4* srcb = (s[k] >= 0) ? features4 : anchor4;
        v[k] = srcb[(size_t)(s[k] & 0x7fffffff) * 128 + c4];
    }
    #pragma unroll
    for (int k = 0; k < kExIters; ++k)
        __builtin_nontemporal_store(v[k], &out4[j0 + k * 256 + t]);
}

// ---------------------------------------------------------------------------
extern "C" void kernel_launch(void* const* d_in, const int* in_sizes, int n_in,
                              void* d_out, int out_size, void* d_ws, size_t ws_size,
                              hipStream_t stream) {
    const float* features = (const float*)d_in[0];   // (B,A,C)
    const float* labels   = (const float*)d_in[1];   // (B,N)
    const float* anchor   = (const float*)d_in[2];   // (N,A,C)
    const float* cache    = (const float*)d_in[3];   // (N,A,C)
    const float* count    = (const float*)d_in[4];   // (N,)
    const float* rand_u   = (const float*)d_in[5];   // (B,A)

    float* out_feat  = (float*)d_out;                // (B,A,C)
    float* out_cache = out_feat + kFeat;             // (N,A,C)
    float* out_count = out_cache + kCache;           // (N,)

    int* cls    = (int*)d_ws;                        // 256 ints
    int* srcrow = cls + kB;                          // 8192 ints

    k_prep<<<kB / 4, 256, 0, stream>>>(labels, rand_u, cls, srcrow);
    k_cache<<<kCacheBlks, 256, 0, stream>>>(features, cache, count, cls,
                                            out_cache, out_count);
    k_exch<<<kExBlks, 256, 0, stream>>>(features, anchor, srcrow, out_feat);
}